// Round 1
// baseline (4658.432 us; speedup 1.0000x reference)
//
#include <hip/hip_runtime.h>

typedef _Float16 h16;
typedef h16 h16x8 __attribute__((ext_vector_type(8)));
typedef float f32x4 __attribute__((ext_vector_type(4)));

#define MFMA16(a, b, c) __builtin_amdgcn_mfma_f32_16x16x32_f16(a, b, c, 0, 0, 0)

typedef __attribute__((address_space(1))) const char gconst_char;
typedef __attribute__((address_space(3))) char lds_char;
#define GL_LDS16(g, l) __builtin_amdgcn_global_load_lds((gconst_char*)(g), (lds_char*)(l), 16, 0, 0)

// ---------------- workspace layout (bytes) ----------------
// Fragment-major fp16 weight blocks: B-fragment f of a chunk lives at
// chunk_base + f*1024 + lane*16. Lane-linear => conflict-free ds_read_b128 with
// immediate offsets, and matches global_load_lds's lane-linear LDS write.
#define WIN_CSH   16384                    // [frag 16][lane 64][16B], 8 chunks
#define WIN_OFF   0
#define WUP_CSH   16384                    // 32 chunks
#define WUP_OFF   131072
#define WDN_CSH   16384                    // [frag 16][lane 64][16B], 32 chunks
#define WDN_OFF   655360
#define WCOMB_CSH 32768                    // [frag 32][lane 64][16B], 8 chunks
#define WCOMB_OFF 1179648
#define WYT_CSH   16384                    // 8 chunks
#define WYT_OFF   1441792
#define WHEAD_SZ  8192                     // [frag 8][lane 64][16B]
#define WHEAD_OFF 1572864
#define ZY_OFF    1581056
#define ZY_BYTES  (131072UL * 512UL * 2UL) // [B][512] halfs: z cols 0..255, y cols 256..511

// ---------------- mega kernel LDS layout ----------------
#define L_WUP0 0
#define L_WUP1 16384
#define L_WDN0 32768
#define L_WDN1 49152
#define L_HS   65536        // + wave*2560 : [32][40] halfs per wave
#define L_ZT   86016        // + wave*8448 : [16][264] halfs per wave (transpose slice)
#define L_BUP  153600       // f32[1024]
#define L_BDN  157696       // f32[256]
#define L_LNW  158720
#define L_LNB  159744
#define SMEM_MEGA 160768

// ---------------- comb kernel LDS layout ----------------
#define C_WC0 0
#define C_WC1 32768
#define C_WY0 65536
#define C_WY1 81920
#define C_GS  98304         // + wave*2560
#define C_BC  118784
#define C_BY  119808
#define SMEM_COMB 120832
// ZT alias for comb: smem[0 .. 67584) per-wave 8448B, only used while weight bufs idle

#define SMEM_HEAD 8192

__device__ __forceinline__ void stage_calls(const char* src, char* dst, int calls, int wave,
                                            int nw, int lane) {
  for (int i = wave; i < calls; i += nw)
    GL_LDS16(src + i * 1024 + lane * 16, dst + i * 1024);
}

__device__ __forceinline__ float gelu_f(float x) {
  float t = x * (1.5957691216f + 0.0713548354f * x * x);
  float e = __expf(-t);
  return x * __builtin_amdgcn_rcpf(1.0f + e);
}

// ================= prep kernels: fp32 -> fp16 fragment-major blocks =================
// prepC: GEMM1-style B operand (z @ W). chunk = 32 output cols, frag = kk*2+nt.
// element at dst[chunk*CSHh + frag*512 + lane*8 + j] = W[kk*32+q*8+j][chunk*32+nt*16+c]
__global__ void prepC_kernel(const float* __restrict__ src, h16* __restrict__ dst,
                             int Nsrc, int CSHh, int tot) {
  for (int d = blockIdx.x * 256 + threadIdx.x; d < tot; d += gridDim.x * 256) {
    int chunk = d / CSHh, r = d % CSHh;
    int frag = r >> 9, lane = (r >> 3) & 63, j = r & 7;
    int kk = frag >> 1, nt = frag & 1, q = lane >> 4, c = lane & 15;
    int k = kk * 32 + q * 8 + j;
    int n = chunk * 32 + nt * 16 + c;
    dst[d] = (h16)src[(long)k * Nsrc + n];
  }
}
// prepD: GEMM2-style B operand (h @ W, chunked over k by 32, N=256). frag = nt.
// dst[chunk*8192 + nt*512 + lane*8 + j] = W[chunk*32+q*8+j][nt*16+c]
__global__ void prepD_kernel(const float* __restrict__ src, h16* __restrict__ dst, int tot) {
  for (int d = blockIdx.x * 256 + threadIdx.x; d < tot; d += gridDim.x * 256) {
    int chunk = d >> 13, r = d & 8191;
    int nt = r >> 9, lane = (r >> 3) & 63, j = r & 7;
    int q = lane >> 4, c = lane & 15;
    int k = chunk * 32 + q * 8 + j;
    dst[d] = (h16)src[(long)k * 256 + nt * 16 + c];
  }
}
// prepH: W_head [256][10] -> [frag 8][lane][8], n = c (cols 10..15 zero)
__global__ void prepH_kernel(const float* __restrict__ src, h16* __restrict__ dst) {
  for (int d = blockIdx.x * 256 + threadIdx.x; d < 4096; d += gridDim.x * 256) {
    int kk = d >> 9, lane = (d >> 3) & 63, j = d & 7;
    int q = lane >> 4, c = lane & 15;
    int k = kk * 32 + q * 8 + j;
    dst[d] = (h16)((c < 10) ? src[k * 10 + c] : 0.0f);
  }
}

// ================= mega kernel: (optional in-proj) + 6 fused FFN+LN iterations =================
__global__ __launch_bounds__(512) void mega_kernel(
    const float* x, h16* zy,
    const char* __restrict__ winP, const char* __restrict__ wupP, const char* __restrict__ wdnP,
    const float* __restrict__ b_in, const float* __restrict__ b_up,
    const float* __restrict__ b_down, const float* __restrict__ ln_w,
    const float* __restrict__ ln_b, const float* __restrict__ y_init, int first) {
  extern __shared__ char smem[];
  const int tid = threadIdx.x, wave = tid >> 6, lane = tid & 63;
  const int q = lane >> 4, c = lane & 15;
  const int lane16 = lane << 4;
  const long m0 = (long)blockIdx.x * 256 + wave * 32;

  float* bupL = (float*)(smem + L_BUP);
  float* bdnL = (float*)(smem + L_BDN);
  float* lnwL = (float*)(smem + L_LNW);
  float* lnbL = (float*)(smem + L_LNB);
  for (int i = tid; i < 1024; i += 512) bupL[i] = b_up[i];
  if (tid < 256) { bdnL[tid] = b_down[tid]; lnwL[tid] = ln_w[tid]; lnbL[tid] = ln_b[tid]; }

  f32x4 acc2[2][16];   // z accumulator, D-layout: row = rt*16 + q*4 + r, col = nt*16 + c
  h16x8 az[2][8];      // A-fragments of z: A[m=c][k=kk*32+q*8+j]
  h16* hsH = (h16*)(smem + L_HS + wave * 2560);
  h16* zth = (h16*)(smem + L_ZT + wave * 8448);
  const f32x4 vzero = {0.0f, 0.0f, 0.0f, 0.0f};

  if (first) {
    // ---- in-proj: z = x @ W_in + b_in ----
#pragma unroll
    for (int rt = 0; rt < 2; ++rt)
#pragma unroll
      for (int kk = 0; kk < 8; ++kk) {
        const float* p = x + (m0 + rt * 16 + c) * 256 + kk * 32 + q * 8;
        f32x4 u0 = *(const f32x4*)p;
        f32x4 u1 = *(const f32x4*)(p + 4);
        h16x8 a;
        a[0] = (h16)u0[0]; a[1] = (h16)u0[1]; a[2] = (h16)u0[2]; a[3] = (h16)u0[3];
        a[4] = (h16)u1[0]; a[5] = (h16)u1[1]; a[6] = (h16)u1[2]; a[7] = (h16)u1[3];
        az[rt][kk] = a;
      }
#pragma unroll
    for (int rt = 0; rt < 2; ++rt)
#pragma unroll
      for (int nt = 0; nt < 16; ++nt) acc2[rt][nt] = vzero;

    stage_calls(winP, smem + L_WUP0, 16, wave, 8, lane);
    __syncthreads();
#pragma unroll
    for (int ncI = 0; ncI < 8; ++ncI) {
      if (ncI < 7)
        stage_calls(winP + (ncI + 1) * WIN_CSH, smem + (((ncI + 1) & 1) ? L_WUP1 : L_WUP0),
                    16, wave, 8, lane);
      const char* wb = smem + ((ncI & 1) ? L_WUP1 : L_WUP0);
#pragma unroll
      for (int kk = 0; kk < 8; ++kk)
#pragma unroll
        for (int nt = 0; nt < 2; ++nt) {
          h16x8 b = *(const h16x8*)(wb + ((kk * 2 + nt) << 10) + lane16);
          acc2[0][ncI * 2 + nt] = MFMA16(az[0][kk], b, acc2[0][ncI * 2 + nt]);
          acc2[1][ncI * 2 + nt] = MFMA16(az[1][kk], b, acc2[1][ncI * 2 + nt]);
        }
      __syncthreads();
    }
#pragma unroll
    for (int nt = 0; nt < 16; ++nt) {
      float bi = b_in[nt * 16 + c];
#pragma unroll
      for (int rt = 0; rt < 2; ++rt)
#pragma unroll
        for (int r = 0; r < 4; ++r) acc2[rt][nt][r] += bi;
    }
    // ---- write y-half = y_init (comb reads it for the concatenated GEMM) ----
#pragma unroll
    for (int kk = 0; kk < 8; ++kk) {
      const float* p = y_init + kk * 32 + q * 8;
      f32x4 u0 = *(const f32x4*)p;
      f32x4 u1 = *(const f32x4*)(p + 4);
      h16x8 a;
      a[0] = (h16)u0[0]; a[1] = (h16)u0[1]; a[2] = (h16)u0[2]; a[3] = (h16)u0[3];
      a[4] = (h16)u1[0]; a[5] = (h16)u1[1]; a[6] = (h16)u1[2]; a[7] = (h16)u1[3];
#pragma unroll
      for (int rt = 0; rt < 2; ++rt)
        *(h16x8*)(zy + (m0 + rt * 16 + c) * 512 + 256 + kk * 32 + q * 8) = a;
    }
    // prologue: stage FFN chunk 0
    stage_calls(wupP, smem + L_WUP0, 16, wave, 8, lane);
    stage_calls(wdnP, smem + L_WDN0, 16, wave, 8, lane);
  } else {
    // prologue staging first, loads fly under the resume work
    stage_calls(wupP, smem + L_WUP0, 16, wave, 8, lane);
    stage_calls(wdnP, smem + L_WDN0, 16, wave, 8, lane);
    // ---- resume z from zy (vectorized); rebuild acc2 via per-wave LDS transpose ----
#pragma unroll
    for (int rt = 0; rt < 2; ++rt)
#pragma unroll
      for (int kk = 0; kk < 8; ++kk)
        az[rt][kk] = *(const h16x8*)(zy + (m0 + rt * 16 + c) * 512 + kk * 32 + q * 8);
#pragma unroll
    for (int rt = 0; rt < 2; ++rt) {
#pragma unroll
      for (int kk = 0; kk < 8; ++kk)
        *(h16x8*)(zth + c * 264 + kk * 32 + q * 8) = az[rt][kk];
#pragma unroll
      for (int nt = 0; nt < 16; ++nt)
#pragma unroll
        for (int r = 0; r < 4; ++r)
          acc2[rt][nt][r] = (float)zth[(q * 4 + r) * 264 + nt * 16 + c];
    }
  }

  for (int it = 0; it < 6; ++it) {
    if (it > 0 || first) {
      // ---- Zt: D-layout z (acc2) -> fp16 A-fragments via private LDS slice ----
#pragma unroll
      for (int rt = 0; rt < 2; ++rt) {
#pragma unroll
        for (int nt = 0; nt < 16; ++nt)
#pragma unroll
          for (int r = 0; r < 4; ++r)
            zth[(q * 4 + r) * 264 + nt * 16 + c] = (h16)acc2[rt][nt][r];
#pragma unroll
        for (int kk = 0; kk < 8; ++kk)
          az[rt][kk] = *(const h16x8*)(zth + c * 264 + kk * 32 + q * 8);
      }
    }

    for (int nc = 0; nc < 32; ++nc) {
      const int tc = it * 32 + nc;
      __syncthreads();  // staged chunk tc landed (loads issued a full chunk ago)
      if (tc < 191) {
        const int nxt = (nc + 1) & 31;
        char* wu = smem + (((tc + 1) & 1) ? L_WUP1 : L_WUP0);
        char* wd = smem + (((tc + 1) & 1) ? L_WDN1 : L_WDN0);
        stage_calls(wupP + nxt * WUP_CSH, wu, 16, wave, 8, lane);
        stage_calls(wdnP + nxt * WDN_CSH, wd, 16, wave, 8, lane);
      }
      const char* wub = smem + ((tc & 1) ? L_WUP1 : L_WUP0);
      const char* wdb = smem + ((tc & 1) ? L_WDN1 : L_WDN0);

      // GEMM1: h_pre = z @ W_up[:, nc*32 : +32]
      f32x4 acc1[2][2];
      acc1[0][0] = vzero; acc1[0][1] = vzero; acc1[1][0] = vzero; acc1[1][1] = vzero;
#pragma unroll
      for (int kk = 0; kk < 8; ++kk)
#pragma unroll
        for (int nt = 0; nt < 2; ++nt) {
          h16x8 b = *(const h16x8*)(wub + ((kk * 2 + nt) << 10) + lane16);
          acc1[0][nt] = MFMA16(az[0][kk], b, acc1[0][nt]);
          acc1[1][nt] = MFMA16(az[1][kk], b, acc1[1][nt]);
        }
      // gelu + bias -> Hs (per-wave)
#pragma unroll
      for (int rt = 0; rt < 2; ++rt)
#pragma unroll
        for (int nt = 0; nt < 2; ++nt) {
          float bu = bupL[nc * 32 + nt * 16 + c];
#pragma unroll
          for (int r = 0; r < 4; ++r) {
            float g = gelu_f(acc1[rt][nt][r] + bu);
            hsH[(rt * 16 + q * 4 + r) * 40 + nt * 16 + c] = (h16)g;
          }
        }
      h16x8 ah0 = *(const h16x8*)(hsH + c * 40 + q * 8);
      h16x8 ah1 = *(const h16x8*)(hsH + (16 + c) * 40 + q * 8);
      // GEMM2: acc2 += h @ W_down[nc*32 : +32, :]
#pragma unroll
      for (int nt = 0; nt < 16; ++nt) {
        h16x8 b = *(const h16x8*)(wdb + (nt << 10) + lane16);
        acc2[0][nt] = MFMA16(ah0, b, acc2[0][nt]);
        acc2[1][nt] = MFMA16(ah1, b, acc2[1][nt]);
      }
    }

    // ---- epilogue: + b_down, LayerNorm (registers, quad-wide butterfly) ----
#pragma unroll
    for (int rt = 0; rt < 2; ++rt) {
      float sum[4] = {0, 0, 0, 0}, sq[4] = {0, 0, 0, 0};
#pragma unroll
      for (int nt = 0; nt < 16; ++nt) {
        float bd = bdnL[nt * 16 + c];
#pragma unroll
        for (int r = 0; r < 4; ++r) {
          float v = acc2[rt][nt][r] + bd;
          acc2[rt][nt][r] = v;
          sum[r] += v;
          sq[r] += v * v;
        }
      }
#pragma unroll
      for (int r = 0; r < 4; ++r)
#pragma unroll
        for (int m = 1; m < 16; m <<= 1) {
          sum[r] += __shfl_xor(sum[r], m, 16);
          sq[r] += __shfl_xor(sq[r], m, 16);
        }
      float mu[4], rs[4];
#pragma unroll
      for (int r = 0; r < 4; ++r) {
        mu[r] = sum[r] * (1.0f / 256.0f);
        float var = sq[r] * (1.0f / 256.0f) - mu[r] * mu[r];
        rs[r] = __builtin_amdgcn_rsqf(var + 1e-5f);
      }
#pragma unroll
      for (int nt = 0; nt < 16; ++nt) {
        float w = lnwL[nt * 16 + c], bb = lnbL[nt * 16 + c];
#pragma unroll
        for (int r = 0; r < 4; ++r)
          acc2[rt][nt][r] = (acc2[rt][nt][r] - mu[r]) * rs[r] * w + bb;
      }
    }
  }

  // ---- hand off z (fp16, vectorized full-line stores via private transpose slice) ----
#pragma unroll
  for (int rt = 0; rt < 2; ++rt) {
#pragma unroll
    for (int nt = 0; nt < 16; ++nt)
#pragma unroll
      for (int r = 0; r < 4; ++r)
        zth[(q * 4 + r) * 264 + nt * 16 + c] = (h16)acc2[rt][nt][r];
#pragma unroll
    for (int kk = 0; kk < 8; ++kk)
      *(h16x8*)(zy + (m0 + rt * 16 + c) * 512 + kk * 32 + q * 8) =
          *(const h16x8*)(zth + c * 264 + kk * 32 + q * 8);
  }
}

// ================= comb kernel: g = gelu([z|y]@W_comb + b_comb); y += g@W_yt + b_yt =================
__global__ __launch_bounds__(512) void comb_kernel(
    h16* zy, const char* __restrict__ wcP, const char* __restrict__ wytP,
    const float* __restrict__ b_comb, const float* __restrict__ b_yt,
    const float* __restrict__ y_init, int first) {
  extern __shared__ char smem[];
  const int tid = threadIdx.x, wave = tid >> 6, lane = tid & 63;
  const int q = lane >> 4, c = lane & 15;
  const int lane16 = lane << 4;
  const long m0 = (long)blockIdx.x * 256 + wave * 32;

  float* bcL = (float*)(smem + C_BC);
  float* byL = (float*)(smem + C_BY);
  if (tid < 256) { bcL[tid] = b_comb[tid]; byL[tid] = b_yt[tid]; }

  f32x4 acc2[2][16];  // y accumulator
  if (first) {
#pragma unroll
    for (int nt = 0; nt < 16; ++nt) {
      float yv = y_init[nt * 16 + c];
#pragma unroll
      for (int rt = 0; rt < 2; ++rt)
#pragma unroll
        for (int r = 0; r < 4; ++r) acc2[rt][nt][r] = yv;
    }
  } else {
    // vectorized y resume via ZT alias (weight bufs not yet staged)
    h16* zth = (h16*)(smem + wave * 8448);
#pragma unroll
    for (int rt = 0; rt < 2; ++rt) {
#pragma unroll
      for (int kk = 0; kk < 8; ++kk)
        *(h16x8*)(zth + c * 264 + kk * 32 + q * 8) =
            *(const h16x8*)(zy + (m0 + rt * 16 + c) * 512 + 256 + kk * 32 + q * 8);
#pragma unroll
      for (int nt = 0; nt < 16; ++nt)
#pragma unroll
        for (int r = 0; r < 4; ++r)
          acc2[rt][nt][r] = (float)zth[(q * 4 + r) * 264 + nt * 16 + c];
    }
  }
  __syncthreads();  // ZT alias region free before staging

  h16* gsH = (h16*)(smem + C_GS + wave * 2560);
  const f32x4 vzero = {0.0f, 0.0f, 0.0f, 0.0f};

  stage_calls(wcP, smem + C_WC0, 32, wave, 8, lane);
  stage_calls(wytP, smem + C_WY0, 16, wave, 8, lane);

  for (int nc = 0; nc < 8; ++nc) {
    __syncthreads();
    if (nc < 7) {
      int nb = (nc + 1) & 1;
      stage_calls(wcP + (nc + 1) * WCOMB_CSH, smem + (nb ? C_WC1 : C_WC0), 32, wave, 8, lane);
      stage_calls(wytP + (nc + 1) * WYT_CSH, smem + (nb ? C_WY1 : C_WY0), 16, wave, 8, lane);
    }
    const char* wcb = smem + ((nc & 1) ? C_WC1 : C_WC0);
    const char* wyb = smem + ((nc & 1) ? C_WY1 : C_WY0);

    // GEMM-g: [z|y] @ W_comb[:, nc*32 : +32]
    f32x4 acc1[2][2];
    acc1[0][0] = vzero; acc1[0][1] = vzero; acc1[1][0] = vzero; acc1[1][1] = vzero;
#pragma unroll
    for (int kk = 0; kk < 16; ++kk) {
      h16x8 a0 = *(const h16x8*)(zy + (m0 + c) * 512 + kk * 32 + q * 8);
      h16x8 a1 = *(const h16x8*)(zy + (m0 + 16 + c) * 512 + kk * 32 + q * 8);
#pragma unroll
      for (int nt = 0; nt < 2; ++nt) {
        h16x8 b = *(const h16x8*)(wcb + ((kk * 2 + nt) << 10) + lane16);
        acc1[0][nt] = MFMA16(a0, b, acc1[0][nt]);
        acc1[1][nt] = MFMA16(a1, b, acc1[1][nt]);
      }
    }
#pragma unroll
    for (int rt = 0; rt < 2; ++rt)
#pragma unroll
      for (int nt = 0; nt < 2; ++nt) {
        float bc = bcL[nc * 32 + nt * 16 + c];
#pragma unroll
        for (int r = 0; r < 4; ++r) {
          float g = gelu_f(acc1[rt][nt][r] + bc);
          gsH[(rt * 16 + q * 4 + r) * 40 + nt * 16 + c] = (h16)g;
        }
      }
    h16x8 ah0 = *(const h16x8*)(gsH + c * 40 + q * 8);
    h16x8 ah1 = *(const h16x8*)(gsH + (16 + c) * 40 + q * 8);
#pragma unroll
    for (int nt = 0; nt < 16; ++nt) {
      h16x8 b = *(const h16x8*)(wyb + (nt << 10) + lane16);
      acc2[0][nt] = MFMA16(ah0, b, acc2[0][nt]);
      acc2[1][nt] = MFMA16(ah1, b, acc2[1][nt]);
    }
  }

  __syncthreads();  // weight bufs idle -> ZT alias free
  h16* zth = (h16*)(smem + wave * 8448);
#pragma unroll
  for (int rt = 0; rt < 2; ++rt) {
#pragma unroll
    for (int nt = 0; nt < 16; ++nt) {
      float by = byL[nt * 16 + c];
#pragma unroll
      for (int r = 0; r < 4; ++r)
        zth[(q * 4 + r) * 264 + nt * 16 + c] = (h16)(acc2[rt][nt][r] + by);
    }
#pragma unroll
    for (int kk = 0; kk < 8; ++kk)
      *(h16x8*)(zy + (m0 + rt * 16 + c) * 512 + 256 + kk * 32 + q * 8) =
          *(const h16x8*)(zth + c * 264 + kk * 32 + q * 8);
  }
}

// ================= head kernel: out = y @ W_head + b_head =================
__global__ __launch_bounds__(256) void head_kernel(const h16* zy, const char* __restrict__ whP,
                                                   const float* __restrict__ b_head,
                                                   float* __restrict__ out) {
  extern __shared__ char smem[];
  const int tid = threadIdx.x, wave = tid >> 6, lane = tid & 63;
  const int q = lane >> 4, c = lane & 15;
  const int lane16 = lane << 4;
  const long m0 = (long)blockIdx.x * 128 + wave * 32;

  stage_calls(whP, smem, 8, wave, 4, lane);
  __syncthreads();

  f32x4 acc[2];
  const f32x4 vzero = {0.0f, 0.0f, 0.0f, 0.0f};
  acc[0] = vzero; acc[1] = vzero;
#pragma unroll
  for (int kk = 0; kk < 8; ++kk) {
    h16x8 b = *(const h16x8*)(smem + (kk << 10) + lane16);
#pragma unroll
    for (int rt = 0; rt < 2; ++rt) {
      h16x8 a = *(const h16x8*)(zy + (m0 + rt * 16 + c) * 512 + 256 + kk * 32 + q * 8);
      acc[rt] = MFMA16(a, b, acc[rt]);
    }
  }
  if (c < 10) {
    float bh = b_head[c];
#pragma unroll
    for (int rt = 0; rt < 2; ++rt)
#pragma unroll
      for (int r = 0; r < 4; ++r)
        out[(m0 + rt * 16 + q * 4 + r) * 10 + c] = acc[rt][r] + bh;
  }
}

// ================= host =================
extern "C" void kernel_launch(void* const* d_in, const int* in_sizes, int n_in, void* d_out,
                              int out_size, void* d_ws, size_t ws_size, hipStream_t stream) {
  (void)in_sizes; (void)n_in; (void)out_size;
  const float* x      = (const float*)d_in[0];
  const float* W_in   = (const float*)d_in[1];
  const float* b_in   = (const float*)d_in[2];
  const float* y_init = (const float*)d_in[3];
  const float* W_up   = (const float*)d_in[4];
  const float* b_up   = (const float*)d_in[5];
  const float* W_down = (const float*)d_in[6];
  const float* b_down = (const float*)d_in[7];
  const float* ln_w   = (const float*)d_in[8];
  const float* ln_b   = (const float*)d_in[9];
  const float* W_comb = (const float*)d_in[10];
  const float* b_comb = (const float*)d_in[11];
  const float* W_yt   = (const float*)d_in[12];
  const float* b_yt   = (const float*)d_in[13];
  const float* W_head = (const float*)d_in[14];
  const float* b_head = (const float*)d_in[15];

  char* ws = (char*)d_ws;
  h16* winP   = (h16*)(ws + WIN_OFF);
  h16* wupP   = (h16*)(ws + WUP_OFF);
  h16* wdnP   = (h16*)(ws + WDN_OFF);
  h16* wcombP = (h16*)(ws + WCOMB_OFF);
  h16* wytP   = (h16*)(ws + WYT_OFF);
  h16* wheadP = (h16*)(ws + WHEAD_OFF);
  h16* zy = (ws_size >= (size_t)ZY_OFF + ZY_BYTES) ? (h16*)(ws + ZY_OFF) : (h16*)d_in[0];

  hipFuncSetAttribute((const void*)mega_kernel, hipFuncAttributeMaxDynamicSharedMemorySize,
                      SMEM_MEGA);
  hipFuncSetAttribute((const void*)comb_kernel, hipFuncAttributeMaxDynamicSharedMemorySize,
                      SMEM_COMB);

  // prep: cast + fragment-major blocking of all weights
  {
    int tot;
    tot = 8 * (WIN_CSH / 2);
    prepC_kernel<<<dim3((tot + 255) / 256), dim3(256), 0, stream>>>(W_in, winP, 256, WIN_CSH / 2, tot);
    tot = 32 * (WUP_CSH / 2);
    prepC_kernel<<<dim3((tot + 255) / 256), dim3(256), 0, stream>>>(W_up, wupP, 1024, WUP_CSH / 2, tot);
    tot = 8 * (WCOMB_CSH / 2);
    prepC_kernel<<<dim3((tot + 255) / 256), dim3(256), 0, stream>>>(W_comb, wcombP, 256, WCOMB_CSH / 2, tot);
    tot = 32 * (WDN_CSH / 2);
    prepD_kernel<<<dim3((tot + 255) / 256), dim3(256), 0, stream>>>(W_down, wdnP, tot);
    tot = 8 * (WYT_CSH / 2);
    prepD_kernel<<<dim3((tot + 255) / 256), dim3(256), 0, stream>>>(W_yt, wytP, tot);
    prepH_kernel<<<dim3(16), dim3(256), 0, stream>>>(W_head, wheadP);
  }

  for (int h = 0; h < 3; ++h) {
    mega_kernel<<<dim3(512), dim3(512), SMEM_MEGA, stream>>>(
        x, zy, (const char*)winP, (const char*)wupP, (const char*)wdnP, b_in, b_up, b_down,
        ln_w, ln_b, y_init, (h == 0) ? 1 : 0);
    comb_kernel<<<dim3(512), dim3(512), SMEM_COMB, stream>>>(
        zy, (const char*)wcombP, (const char*)wytP, b_comb, b_yt, y_init, (h == 0) ? 1 : 0);
  }
  head_kernel<<<dim3(1024), dim3(256), SMEM_HEAD, stream>>>(zy, (const char*)wheadP, b_head,
                                                            (float*)d_out);
}

// Round 2
// 4109.492 us; speedup vs baseline: 1.1336x; 1.1336x over previous
//
#include <hip/hip_runtime.h>

typedef _Float16 h16;
typedef h16 h16x8 __attribute__((ext_vector_type(8)));
typedef float f32x4 __attribute__((ext_vector_type(4)));

#define MFMA16(a, b, c) __builtin_amdgcn_mfma_f32_16x16x32_f16(a, b, c, 0, 0, 0)

typedef __attribute__((address_space(1))) const char gconst_char;
typedef __attribute__((address_space(3))) char lds_char;
#define GL_LDS16(g, l) __builtin_amdgcn_global_load_lds((gconst_char*)(g), (lds_char*)(l), 16, 0, 0)

// ---------------- workspace layout (bytes) ----------------
// Fragment-major fp16 weight blocks: B-fragment f of a chunk lives at
// chunk_base + f*1024 + lane*16. Lane-linear => conflict-free ds_read_b128 with
// immediate offsets, and matches global_load_lds's lane-linear LDS write.
#define WIN_CSH   16384                    // [frag 16][lane 64][16B], 8 chunks
#define WIN_OFF   0
#define WUP_CSH   16384                    // 32 chunks
#define WUP_OFF   131072
#define WDN_CSH   16384                    // [frag 16][lane 64][16B], 32 chunks
#define WDN_OFF   655360
#define WCOMB_CSH 32768                    // [frag 32][lane 64][16B], 8 chunks
#define WCOMB_OFF 1179648
#define WYT_CSH   16384                    // 8 chunks
#define WYT_OFF   1441792
#define WHEAD_SZ  8192                     // [frag 8][lane 64][16B]
#define WHEAD_OFF 1572864
#define ZY_OFF    1581056
#define ZY_BYTES  (131072UL * 512UL * 2UL) // [B][512] halfs: z cols 0..255, y cols 256..511

// ---------------- mega kernel LDS layout (4 waves, 2 blocks/CU) ----------------
#define L_WUP0 0
#define L_WUP1 16384
#define L_WDN0 32768
#define L_WDN1 49152
#define L_HS   65536        // + wave*2560 : [32][40] halfs (chunk) / [16][72] halfs (transpose)
#define L_BDN  75776        // f32[256]
#define L_LNW  76800
#define L_LNB  77824
#define SMEM_MEGA 78848     // 163840/78848 = 2 blocks/CU

// ---------------- comb kernel LDS layout (8 waves) ----------------
#define C_WC0 0
#define C_WC1 32768
#define C_WY0 65536
#define C_WY1 81920
#define C_GS  98304         // + wave*2560
#define C_BC  118784
#define C_BY  119808
#define SMEM_COMB 120832

#define SMEM_HEAD 8192

__device__ __forceinline__ void stage_calls(const char* src, char* dst, int calls, int wave,
                                            int nw, int lane) {
  for (int i = wave; i < calls; i += nw)
    GL_LDS16(src + i * 1024 + lane * 16, dst + i * 1024);
}

__device__ __forceinline__ float gelu_f(float x) {
  float t = x * (1.5957691216f + 0.0713548354f * x * x);
  float e = __expf(-t);
  return x * __builtin_amdgcn_rcpf(1.0f + e);
}

// ---- multipass transposes through a per-wave [16][72] fp16 slice (<=2304B) ----
// D-layout: lane holds (row q*4+r, col nt*16+c).  A-frag kk: lane holds (row c, cols kk*32+q*8+j).
// Stride 72 halfs = 36 dwords -> b128 reads land 8 lanes per 4-bank group: conflict-free.
__device__ __forceinline__ void d2a_rt(const f32x4* accRt, h16x8* azRt, h16* sl, int q, int c) {
#pragma unroll
  for (int cc = 0; cc < 4; ++cc) {
#pragma unroll
    for (int ntp = 0; ntp < 4; ++ntp)
#pragma unroll
      for (int r = 0; r < 4; ++r)
        sl[(q * 4 + r) * 72 + ntp * 16 + c] = (h16)accRt[cc * 4 + ntp][r];
#pragma unroll
    for (int k2 = 0; k2 < 2; ++k2)
      azRt[cc * 2 + k2] = *(const h16x8*)(sl + c * 72 + k2 * 32 + q * 8);
  }
}
__device__ __forceinline__ void a2d_rt(const h16x8* azRt, f32x4* accRt, h16* sl, int q, int c) {
#pragma unroll
  for (int cc = 0; cc < 4; ++cc) {
#pragma unroll
    for (int k2 = 0; k2 < 2; ++k2)
      *(h16x8*)(sl + c * 72 + k2 * 32 + q * 8) = azRt[cc * 2 + k2];
#pragma unroll
    for (int ntp = 0; ntp < 4; ++ntp)
#pragma unroll
      for (int r = 0; r < 4; ++r)
        accRt[cc * 4 + ntp][r] = (float)sl[(q * 4 + r) * 72 + ntp * 16 + c];
  }
}
// D-layout -> row-major fp16 global (16B/lane stores), gdst = row base (stride 512 halfs)
__device__ __forceinline__ void d2g_rt(const f32x4* accRt, h16* sl, h16* gdst, int q, int c) {
#pragma unroll
  for (int cc = 0; cc < 4; ++cc) {
#pragma unroll
    for (int ntp = 0; ntp < 4; ++ntp)
#pragma unroll
      for (int r = 0; r < 4; ++r)
        sl[(q * 4 + r) * 72 + ntp * 16 + c] = (h16)accRt[cc * 4 + ntp][r];
#pragma unroll
    for (int k2 = 0; k2 < 2; ++k2)
      *(h16x8*)(gdst + (long)c * 512 + cc * 64 + k2 * 32 + q * 8) =
          *(const h16x8*)(sl + c * 72 + k2 * 32 + q * 8);
  }
}

// ================= prep kernels: fp32 -> fp16 fragment-major blocks =================
__global__ void prepC_kernel(const float* __restrict__ src, h16* __restrict__ dst,
                             int Nsrc, int CSHh, int tot) {
  for (int d = blockIdx.x * 256 + threadIdx.x; d < tot; d += gridDim.x * 256) {
    int chunk = d / CSHh, r = d % CSHh;
    int frag = r >> 9, lane = (r >> 3) & 63, j = r & 7;
    int kk = frag >> 1, nt = frag & 1, q = lane >> 4, c = lane & 15;
    int k = kk * 32 + q * 8 + j;
    int n = chunk * 32 + nt * 16 + c;
    dst[d] = (h16)src[(long)k * Nsrc + n];
  }
}
__global__ void prepD_kernel(const float* __restrict__ src, h16* __restrict__ dst, int tot) {
  for (int d = blockIdx.x * 256 + threadIdx.x; d < tot; d += gridDim.x * 256) {
    int chunk = d >> 13, r = d & 8191;
    int nt = r >> 9, lane = (r >> 3) & 63, j = r & 7;
    int q = lane >> 4, c = lane & 15;
    int k = chunk * 32 + q * 8 + j;
    dst[d] = (h16)src[(long)k * 256 + nt * 16 + c];
  }
}
__global__ void prepH_kernel(const float* __restrict__ src, h16* __restrict__ dst) {
  for (int d = blockIdx.x * 256 + threadIdx.x; d < 4096; d += gridDim.x * 256) {
    int kk = d >> 9, lane = (d >> 3) & 63, j = d & 7;
    int q = lane >> 4, c = lane & 15;
    int k = kk * 32 + q * 8 + j;
    dst[d] = (h16)((c < 10) ? src[k * 10 + c] : 0.0f);
  }
}

// ================= mega kernel: (optional in-proj) + 6 fused FFN+LN iterations =================
// 256 thr (4 waves), 128 rows/block, 1024 blocks. 2 blocks/CU -> phase decorrelation.
__global__ __launch_bounds__(256, 2) void mega_kernel(
    const float* x, h16* zy,
    const char* __restrict__ winP, const char* __restrict__ wupP, const char* __restrict__ wdnP,
    const float* __restrict__ b_in, const float* __restrict__ b_up,
    const float* __restrict__ b_down, const float* __restrict__ ln_w,
    const float* __restrict__ ln_b, const float* __restrict__ y_init, int first) {
  extern __shared__ char smem[];
  const int tid = threadIdx.x, wave = tid >> 6, lane = tid & 63;
  const int q = lane >> 4, c = lane & 15;
  const int lane16 = lane << 4;
  const long m0 = (long)blockIdx.x * 128 + wave * 32;

  float* bdnL = (float*)(smem + L_BDN);
  float* lnwL = (float*)(smem + L_LNW);
  float* lnbL = (float*)(smem + L_LNB);
  bdnL[tid] = b_down[tid]; lnwL[tid] = ln_w[tid]; lnbL[tid] = ln_b[tid];

  f32x4 acc2[2][16];   // z accumulator, D-layout
  h16x8 az[2][8];      // A-fragments of z
  h16* hsH = (h16*)(smem + L_HS + wave * 2560);
  const f32x4 vzero = {0.0f, 0.0f, 0.0f, 0.0f};

  if (first) {
    // ---- in-proj: z = x @ W_in + b_in ----
#pragma unroll
    for (int rt = 0; rt < 2; ++rt)
#pragma unroll
      for (int kk = 0; kk < 8; ++kk) {
        const float* p = x + (m0 + rt * 16 + c) * 256 + kk * 32 + q * 8;
        f32x4 u0 = *(const f32x4*)p;
        f32x4 u1 = *(const f32x4*)(p + 4);
        h16x8 a;
        a[0] = (h16)u0[0]; a[1] = (h16)u0[1]; a[2] = (h16)u0[2]; a[3] = (h16)u0[3];
        a[4] = (h16)u1[0]; a[5] = (h16)u1[1]; a[6] = (h16)u1[2]; a[7] = (h16)u1[3];
        az[rt][kk] = a;
      }
#pragma unroll
    for (int rt = 0; rt < 2; ++rt)
#pragma unroll
      for (int nt = 0; nt < 16; ++nt) acc2[rt][nt] = vzero;

    stage_calls(winP, smem + L_WUP0, 16, wave, 4, lane);
    __syncthreads();
#pragma unroll
    for (int ncI = 0; ncI < 8; ++ncI) {
      if (ncI < 7)
        stage_calls(winP + (ncI + 1) * WIN_CSH, smem + (((ncI + 1) & 1) ? L_WUP1 : L_WUP0),
                    16, wave, 4, lane);
      const char* wb = smem + ((ncI & 1) ? L_WUP1 : L_WUP0);
#pragma unroll
      for (int kk = 0; kk < 8; ++kk)
#pragma unroll
        for (int nt = 0; nt < 2; ++nt) {
          h16x8 b = *(const h16x8*)(wb + ((kk * 2 + nt) << 10) + lane16);
          acc2[0][ncI * 2 + nt] = MFMA16(az[0][kk], b, acc2[0][ncI * 2 + nt]);
          acc2[1][ncI * 2 + nt] = MFMA16(az[1][kk], b, acc2[1][ncI * 2 + nt]);
        }
      __syncthreads();
    }
#pragma unroll
    for (int nt = 0; nt < 16; ++nt) {
      float bi = b_in[nt * 16 + c];
#pragma unroll
      for (int rt = 0; rt < 2; ++rt)
#pragma unroll
        for (int r = 0; r < 4; ++r) acc2[rt][nt][r] += bi;
    }
    // ---- y-half = y_init (comb's concatenated GEMM reads it; fixed absmax 4x) ----
#pragma unroll
    for (int kk = 0; kk < 8; ++kk) {
      const float* p = y_init + kk * 32 + q * 8;
      f32x4 u0 = *(const f32x4*)p;
      f32x4 u1 = *(const f32x4*)(p + 4);
      h16x8 a;
      a[0] = (h16)u0[0]; a[1] = (h16)u0[1]; a[2] = (h16)u0[2]; a[3] = (h16)u0[3];
      a[4] = (h16)u1[0]; a[5] = (h16)u1[1]; a[6] = (h16)u1[2]; a[7] = (h16)u1[3];
#pragma unroll
      for (int rt = 0; rt < 2; ++rt)
        *(h16x8*)(zy + (m0 + rt * 16 + c) * 512 + 256 + kk * 32 + q * 8) = a;
    }
    stage_calls(wupP, smem + L_WUP0, 16, wave, 4, lane);
    stage_calls(wdnP, smem + L_WDN0, 16, wave, 4, lane);
    // az := A-fragments of z (not x) for iteration 0
#pragma unroll
    for (int rt = 0; rt < 2; ++rt) d2a_rt(acc2[rt], az[rt], hsH, q, c);
  } else {
    stage_calls(wupP, smem + L_WUP0, 16, wave, 4, lane);
    stage_calls(wdnP, smem + L_WDN0, 16, wave, 4, lane);
    // resume z: A-form native in zy, D-form via multipass slice
#pragma unroll
    for (int rt = 0; rt < 2; ++rt)
#pragma unroll
      for (int kk = 0; kk < 8; ++kk)
        az[rt][kk] = *(const h16x8*)(zy + (m0 + rt * 16 + c) * 512 + kk * 32 + q * 8);
#pragma unroll
    for (int rt = 0; rt < 2; ++rt) a2d_rt(az[rt], acc2[rt], hsH, q, c);
  }

  for (int it = 0; it < 6; ++it) {
    for (int nc = 0; nc < 32; ++nc) {
      const int tc = it * 32 + nc;
      __syncthreads();  // staged chunk tc landed (its loads were issued a full chunk ago)
      if (tc < 191) {
        const int nxt = (nc + 1) & 31;
        char* wu = smem + (((tc + 1) & 1) ? L_WUP1 : L_WUP0);
        char* wd = smem + (((tc + 1) & 1) ? L_WDN1 : L_WDN0);
        stage_calls(wupP + nxt * WUP_CSH, wu, 16, wave, 4, lane);
        stage_calls(wdnP + nxt * WDN_CSH, wd, 16, wave, 4, lane);
      }
      float bu0 = b_up[nc * 32 + c];        // L1-hot scalars, hidden under GEMM1
      float bu1 = b_up[nc * 32 + 16 + c];
      const char* wub = smem + ((tc & 1) ? L_WUP1 : L_WUP0);
      const char* wdb = smem + ((tc & 1) ? L_WDN1 : L_WDN0);

      // GEMM1: h_pre = z @ W_up[:, nc*32 : +32]
      f32x4 acc1[2][2];
      acc1[0][0] = vzero; acc1[0][1] = vzero; acc1[1][0] = vzero; acc1[1][1] = vzero;
#pragma unroll
      for (int kk = 0; kk < 8; ++kk)
#pragma unroll
        for (int nt = 0; nt < 2; ++nt) {
          h16x8 b = *(const h16x8*)(wub + ((kk * 2 + nt) << 10) + lane16);
          acc1[0][nt] = MFMA16(az[0][kk], b, acc1[0][nt]);
          acc1[1][nt] = MFMA16(az[1][kk], b, acc1[1][nt]);
        }
      // gelu + bias -> Hs (per-wave)
#pragma unroll
      for (int rt = 0; rt < 2; ++rt)
#pragma unroll
        for (int nt = 0; nt < 2; ++nt) {
          float bu = nt ? bu1 : bu0;
#pragma unroll
          for (int r = 0; r < 4; ++r) {
            float g = gelu_f(acc1[rt][nt][r] + bu);
            hsH[(rt * 16 + q * 4 + r) * 40 + nt * 16 + c] = (h16)g;
          }
        }
      h16x8 ah0 = *(const h16x8*)(hsH + c * 40 + q * 8);
      h16x8 ah1 = *(const h16x8*)(hsH + (16 + c) * 40 + q * 8);
      // GEMM2: acc2 += h @ W_down[nc*32 : +32, :]
#pragma unroll
      for (int nt = 0; nt < 16; ++nt) {
        h16x8 b = *(const h16x8*)(wdb + (nt << 10) + lane16);
        acc2[0][nt] = MFMA16(ah0, b, acc2[0][nt]);
        acc2[1][nt] = MFMA16(ah1, b, acc2[1][nt]);
      }
    }

    // ---- fused epilogue: + b_down, LayerNorm normalize-in-place ----
#pragma unroll
    for (int rt = 0; rt < 2; ++rt) {
      float sum[4] = {0, 0, 0, 0}, sq[4] = {0, 0, 0, 0};
#pragma unroll
      for (int nt = 0; nt < 16; ++nt) {
        float bd = bdnL[nt * 16 + c];
#pragma unroll
        for (int r = 0; r < 4; ++r) {
          float v = acc2[rt][nt][r] + bd;
          acc2[rt][nt][r] = v;
          sum[r] += v;
          sq[r] += v * v;
        }
      }
#pragma unroll
      for (int r = 0; r < 4; ++r)
#pragma unroll
        for (int m = 1; m < 16; m <<= 1) {
          sum[r] += __shfl_xor(sum[r], m, 16);
          sq[r] += __shfl_xor(sq[r], m, 16);
        }
      float mu[4], rs[4];
#pragma unroll
      for (int r = 0; r < 4; ++r) {
        mu[r] = sum[r] * (1.0f / 256.0f);
        float var = sq[r] * (1.0f / 256.0f) - mu[r] * mu[r];
        rs[r] = __builtin_amdgcn_rsqf(var + 1e-5f);
      }
#pragma unroll
      for (int nt = 0; nt < 16; ++nt) {
        float w = lnwL[nt * 16 + c], bb = lnbL[nt * 16 + c];
#pragma unroll
        for (int r = 0; r < 4; ++r)
          acc2[rt][nt][r] = (acc2[rt][nt][r] - mu[r]) * rs[r] * w + bb;
      }
      if (it < 5) d2a_rt(acc2[rt], az[rt], hsH, q, c);  // A-frags for next iteration
    }
  }

  // ---- hand off z (fp16, full-line stores via multipass slice) ----
#pragma unroll
  for (int rt = 0; rt < 2; ++rt)
    d2g_rt(acc2[rt], hsH, zy + (m0 + rt * 16) * 512, q, c);
}

// ================= comb kernel: g = gelu([z|y]@W_comb + b_comb); y += g@W_yt + b_yt =================
__global__ __launch_bounds__(512) void comb_kernel(
    h16* zy, const char* __restrict__ wcP, const char* __restrict__ wytP,
    const float* __restrict__ b_comb, const float* __restrict__ b_yt,
    const float* __restrict__ y_init, int first) {
  extern __shared__ char smem[];
  const int tid = threadIdx.x, wave = tid >> 6, lane = tid & 63;
  const int q = lane >> 4, c = lane & 15;
  const int lane16 = lane << 4;
  const long m0 = (long)blockIdx.x * 256 + wave * 32;

  float* bcL = (float*)(smem + C_BC);
  float* byL = (float*)(smem + C_BY);
  if (tid < 256) { bcL[tid] = b_comb[tid]; byL[tid] = b_yt[tid]; }

  h16* gsH = (h16*)(smem + C_GS + wave * 2560);
  const f32x4 vzero = {0.0f, 0.0f, 0.0f, 0.0f};

  stage_calls(wcP, smem + C_WC0, 32, wave, 8, lane);
  stage_calls(wytP, smem + C_WY0, 16, wave, 8, lane);

  f32x4 acc2[2][16];  // y accumulator
  if (first) {
#pragma unroll
    for (int nt = 0; nt < 16; ++nt) {
      float yv = y_init[nt * 16 + c];
#pragma unroll
      for (int rt = 0; rt < 2; ++rt)
#pragma unroll
        for (int r = 0; r < 4; ++r) acc2[rt][nt][r] = yv;
    }
  } else {
    // vectorized y resume via per-wave multipass slice
#pragma unroll
    for (int rt = 0; rt < 2; ++rt) {
      h16x8 yf[8];
#pragma unroll
      for (int kk = 0; kk < 8; ++kk)
        yf[kk] = *(const h16x8*)(zy + (m0 + rt * 16 + c) * 512 + 256 + kk * 32 + q * 8);
      a2d_rt(yf, acc2[rt], gsH, q, c);
    }
  }

  for (int nc = 0; nc < 8; ++nc) {
    __syncthreads();
    if (nc < 7) {
      int nb = (nc + 1) & 1;
      stage_calls(wcP + (nc + 1) * WCOMB_CSH, smem + (nb ? C_WC1 : C_WC0), 32, wave, 8, lane);
      stage_calls(wytP + (nc + 1) * WYT_CSH, smem + (nb ? C_WY1 : C_WY0), 16, wave, 8, lane);
    }
    const char* wcb = smem + ((nc & 1) ? C_WC1 : C_WC0);
    const char* wyb = smem + ((nc & 1) ? C_WY1 : C_WY0);

    // GEMM-g: [z|y] @ W_comb[:, nc*32 : +32]  (zy row IS the concatenated 512-vector)
    f32x4 acc1[2][2];
    acc1[0][0] = vzero; acc1[0][1] = vzero; acc1[1][0] = vzero; acc1[1][1] = vzero;
#pragma unroll
    for (int kk = 0; kk < 16; ++kk) {
      h16x8 a0 = *(const h16x8*)(zy + (m0 + c) * 512 + kk * 32 + q * 8);
      h16x8 a1 = *(const h16x8*)(zy + (m0 + 16 + c) * 512 + kk * 32 + q * 8);
#pragma unroll
      for (int nt = 0; nt < 2; ++nt) {
        h16x8 b = *(const h16x8*)(wcb + ((kk * 2 + nt) << 10) + lane16);
        acc1[0][nt] = MFMA16(a0, b, acc1[0][nt]);
        acc1[1][nt] = MFMA16(a1, b, acc1[1][nt]);
      }
    }
#pragma unroll
    for (int rt = 0; rt < 2; ++rt)
#pragma unroll
      for (int nt = 0; nt < 2; ++nt) {
        float bc = bcL[nc * 32 + nt * 16 + c];
#pragma unroll
        for (int r = 0; r < 4; ++r) {
          float g = gelu_f(acc1[rt][nt][r] + bc);
          gsH[(rt * 16 + q * 4 + r) * 40 + nt * 16 + c] = (h16)g;
        }
      }
    h16x8 ah0 = *(const h16x8*)(gsH + c * 40 + q * 8);
    h16x8 ah1 = *(const h16x8*)(gsH + (16 + c) * 40 + q * 8);
#pragma unroll
    for (int nt = 0; nt < 16; ++nt) {
      h16x8 b = *(const h16x8*)(wyb + (nt << 10) + lane16);
      acc2[0][nt] = MFMA16(ah0, b, acc2[0][nt]);
      acc2[1][nt] = MFMA16(ah1, b, acc2[1][nt]);
    }
  }

  // ---- y store: + b_yt, multipass slice, full-line stores ----
#pragma unroll
  for (int rt = 0; rt < 2; ++rt) {
#pragma unroll
    for (int nt = 0; nt < 16; ++nt) {
      float by = byL[nt * 16 + c];
#pragma unroll
      for (int r = 0; r < 4; ++r) acc2[rt][nt][r] += by;
    }
    d2g_rt(acc2[rt], gsH, zy + (m0 + rt * 16) * 512 + 256, q, c);
  }
}

// ================= head kernel: out = y @ W_head + b_head =================
__global__ __launch_bounds__(256) void head_kernel(const h16* zy, const char* __restrict__ whP,
                                                   const float* __restrict__ b_head,
                                                   float* __restrict__ out) {
  extern __shared__ char smem[];
  const int tid = threadIdx.x, wave = tid >> 6, lane = tid & 63;
  const int q = lane >> 4, c = lane & 15;
  const int lane16 = lane << 4;
  const long m0 = (long)blockIdx.x * 128 + wave * 32;

  stage_calls(whP, smem, 8, wave, 4, lane);
  __syncthreads();

  f32x4 acc[2];
  const f32x4 vzero = {0.0f, 0.0f, 0.0f, 0.0f};
  acc[0] = vzero; acc[1] = vzero;
#pragma unroll
  for (int kk = 0; kk < 8; ++kk) {
    h16x8 b = *(const h16x8*)(smem + (kk << 10) + lane16);
#pragma unroll
    for (int rt = 0; rt < 2; ++rt) {
      h16x8 a = *(const h16x8*)(zy + (m0 + rt * 16 + c) * 512 + 256 + kk * 32 + q * 8);
      acc[rt] = MFMA16(a, b, acc[rt]);
    }
  }
  if (c < 10) {
    float bh = b_head[c];
#pragma unroll
    for (int rt = 0; rt < 2; ++rt)
#pragma unroll
      for (int r = 0; r < 4; ++r)
        out[(m0 + rt * 16 + q * 4 + r) * 10 + c] = acc[rt][r] + bh;
  }
}

// ================= host =================
extern "C" void kernel_launch(void* const* d_in, const int* in_sizes, int n_in, void* d_out,
                              int out_size, void* d_ws, size_t ws_size, hipStream_t stream) {
  (void)in_sizes; (void)n_in; (void)out_size;
  const float* x      = (const float*)d_in[0];
  const float* W_in   = (const float*)d_in[1];
  const float* b_in   = (const float*)d_in[2];
  const float* y_init = (const float*)d_in[3];
  const float* W_up   = (const float*)d_in[4];
  const float* b_up   = (const float*)d_in[5];
  const float* W_down = (const float*)d_in[6];
  const float* b_down = (const float*)d_in[7];
  const float* ln_w   = (const float*)d_in[8];
  const float* ln_b   = (const float*)d_in[9];
  const float* W_comb = (const float*)d_in[10];
  const float* b_comb = (const float*)d_in[11];
  const float* W_yt   = (const float*)d_in[12];
  const float* b_yt   = (const float*)d_in[13];
  const float* W_head = (const float*)d_in[14];
  const float* b_head = (const float*)d_in[15];

  char* ws = (char*)d_ws;
  h16* winP   = (h16*)(ws + WIN_OFF);
  h16* wupP   = (h16*)(ws + WUP_OFF);
  h16* wdnP   = (h16*)(ws + WDN_OFF);
  h16* wcombP = (h16*)(ws + WCOMB_OFF);
  h16* wytP   = (h16*)(ws + WYT_OFF);
  h16* wheadP = (h16*)(ws + WHEAD_OFF);
  h16* zy = (ws_size >= (size_t)ZY_OFF + ZY_BYTES) ? (h16*)(ws + ZY_OFF) : (h16*)d_in[0];

  hipFuncSetAttribute((const void*)mega_kernel, hipFuncAttributeMaxDynamicSharedMemorySize,
                      SMEM_MEGA);
  hipFuncSetAttribute((const void*)comb_kernel, hipFuncAttributeMaxDynamicSharedMemorySize,
                      SMEM_COMB);

  // prep: cast + fragment-major blocking of all weights
  {
    int tot;
    tot = 8 * (WIN_CSH / 2);
    prepC_kernel<<<dim3((tot + 255) / 256), dim3(256), 0, stream>>>(W_in, winP, 256, WIN_CSH / 2, tot);
    tot = 32 * (WUP_CSH / 2);
    prepC_kernel<<<dim3((tot + 255) / 256), dim3(256), 0, stream>>>(W_up, wupP, 1024, WUP_CSH / 2, tot);
    tot = 8 * (WCOMB_CSH / 2);
    prepC_kernel<<<dim3((tot + 255) / 256), dim3(256), 0, stream>>>(W_comb, wcombP, 256, WCOMB_CSH / 2, tot);
    tot = 32 * (WDN_CSH / 2);
    prepD_kernel<<<dim3((tot + 255) / 256), dim3(256), 0, stream>>>(W_down, wdnP, tot);
    tot = 8 * (WYT_CSH / 2);
    prepD_kernel<<<dim3((tot + 255) / 256), dim3(256), 0, stream>>>(W_yt, wytP, tot);
    prepH_kernel<<<dim3(16), dim3(256), 0, stream>>>(W_head, wheadP);
  }

  for (int h = 0; h < 3; ++h) {
    mega_kernel<<<dim3(1024), dim3(256), SMEM_MEGA, stream>>>(
        x, zy, (const char*)winP, (const char*)wupP, (const char*)wdnP, b_in, b_up, b_down,
        ln_w, ln_b, y_init, (h == 0) ? 1 : 0);
    comb_kernel<<<dim3(512), dim3(512), SMEM_COMB, stream>>>(
        zy, (const char*)wcombP, (const char*)wytP, b_comb, b_yt, y_init, (h == 0) ? 1 : 0);
  }
  head_kernel<<<dim3(1024), dim3(256), SMEM_HEAD, stream>>>(zy, (const char*)wheadP, b_head,
                                                            (float*)d_out);
}